// Round 5
// baseline (3664.730 us; speedup 1.0000x reference)
//
#include <hip/hip_runtime.h>
#include <math.h>

#define HH 512
#define DD 512
#define BB 64
#define SS 256
#define KK 1024
#define CC 5

typedef __attribute__((ext_vector_type(8))) short short8;
typedef __attribute__((ext_vector_type(4))) float float4v;

// ---- workspace layout (bytes) ----  total 101,188,608 B
#define OFF_XEF     0u               // 256 s x 2 sp x 64 b x 512 k shorts = 33.5 MB
#define OFF_HSPL    33554432u        // [2 sp][2 phase][2 dir][64 b][512 k] shorts
#define OFF_FLG     34078720u        // 256 x 4B flags
#define OFF_HIST    34079744u        // 2 x 256 x 512 x 64 fp32 = 67 MB
#define OFF_POOLED  OFF_HSPL         // pooled overlays hspl (dead after recurrence)
#define HSPL_PLANE  131072           // shorts per split plane

__device__ __forceinline__ unsigned f2bf_bits(float f) {
    unsigned u = __builtin_bit_cast(unsigned, f);
    return (u + 0x7fffu + ((u >> 16) & 1u)) >> 16;   // RNE
}
__device__ __forceinline__ float sigm_(float v) {
    return 1.f / (1.f + expf(-v));
}
__device__ __forceinline__ float tanh_(float v) {
    return tanhf(v);
}

// ---------------------------------------------------------------------------
// Gather embeddings + split hi/lo bf16 into xef[s][sp][b][k].
// ---------------------------------------------------------------------------
__global__ __launch_bounds__(256)
void gather_split_k(const int* __restrict__ x, const float* __restrict__ embed,
                    short* __restrict__ xef)
{
    const int s   = blockIdx.x;
    const int tid = threadIdx.x;
    const int b   = tid & 63;
    const int seg = tid >> 6;            // 4 segs x 128 k
    __shared__ int rows[BB];
    if (tid < BB) rows[tid] = x[tid * SS + s];   // x is [B][S]
    __syncthreads();
    const float* e = embed + (size_t)rows[b] * DD + seg * 128;
    short* oh = xef + ((size_t)(s * 2 + 0) * BB + b) * 512 + seg * 128;
    short* ol = xef + ((size_t)(s * 2 + 1) * BB + b) * 512 + seg * 128;
    for (int k0 = 0; k0 < 128; k0 += 8) {
        const float4 a = *(const float4*)(e + k0);
        const float4 c = *(const float4*)(e + k0 + 4);
        const float ev[8] = {a.x, a.y, a.z, a.w, c.x, c.y, c.z, c.w};
        short8 vh, vl;
        #pragma unroll
        for (int j = 0; j < 8; ++j) {
            const unsigned hib = f2bf_bits(ev[j]);
            const float hif = __builtin_bit_cast(float, hib << 16);
            const unsigned lob = f2bf_bits(ev[j] - hif);
            vh[j] = (short)hib;
            vl[j] = (short)lob;
        }
        *(short8*)(oh + k0) = vh;
        *(short8*)(ol + k0) = vl;
    }
}

// ---------------------------------------------------------------------------
__global__ __launch_bounds__(256)
void zero_k(unsigned* __restrict__ base, int ndw)
{
    int i = blockIdx.x * 256 + threadIdx.x;
    const int stride = gridDim.x * 256;
    for (; i < ndw; i += stride) base[i] = 0u;
}

// ---------------------------------------------------------------------------
// Cooperative recurrence: R12 re-tiling. 128 WGs (64/dir) x 256 thr, each WG
// owns 8 h x 64 b (was 4 h x 64 b over 256 WGs). Rationale: the h-part is a
// broadcast over the L2-bypass (agent-scope) path; issued bypass traffic per
// dir = 64MB / h_range, so h_range 4->8 HALVES it (32->16 MB/step). Each wave
// keeps its 16-b block and computes TWO m-tiles (mt=0/1) reusing the SAME
// x/h fragments -> per-thread load stream identical in form to the proven
// R3 kernel; only W-LDS (128KB), MFMA count (x2), exchange/publish indexing,
// and the flag group (64/dir) change. Protocol identical.
// ---------------------------------------------------------------------------
__global__ void __launch_bounds__(256, 1)
bilstm_recur_k(const short* __restrict__ xef,
               const float* __restrict__ fwd_W, const float* __restrict__ bwd_W,
               const float* __restrict__ fwd_b, const float* __restrict__ bwd_b,
               short* __restrict__ hspl, float* __restrict__ hist,
               unsigned* __restrict__ flg)
{
    extern __shared__ char smem[];
    short8* wlds = (short8*)smem;                           // 128 KB W fragments
    float*  ex   = (float*)(smem + 131072);                 // 8 KB exchange
    unsigned short* stg = (unsigned short*)(smem + 139264); // 2 KB publish stage

    const int w      = blockIdx.x;
    const int dir    = w >> 6;
    const int wlocal = w & 63;
    const int h0     = wlocal << 3;        // 8 h per WG
    const int tid    = threadIdx.x;
    const int lane   = tid & 63;
    const int wv     = __builtin_amdgcn_readfirstlane(tid >> 6);
    const int nn     = lane & 15;
    const int quad   = lane >> 4;
    const int b      = (wv << 4) + nn;     // wave wv owns b = wv*16 .. +15

    // ---- pack this WG's W fragments into LDS (f2bf_bits split, same bit
    //      pattern as before; now two m-tiles mt=0/1 covering h0..h0+7) ----
    {
        const float* W = dir ? bwd_W : fwd_W;
        const int m  = lane & 15;
        const int g  = m >> 2;
        const int hh = m & 3;
        #pragma unroll
        for (int mt = 0; mt < 2; ++mt) {
            const float* wrow = W + ((size_t)g * HH + h0 + mt * 4 + hh) * KK + quad * 8;
            for (int kk = 0; kk < 8; ++kk) {
                const int kt = wv * 8 + kk;          // 4 waves x 8 = 32 kt
                const float4 a  = *(const float4*)(wrow + kt * 32);
                const float4 c4 = *(const float4*)(wrow + kt * 32 + 4);
                const float ev[8] = {a.x, a.y, a.z, a.w, c4.x, c4.y, c4.z, c4.w};
                short8 vh, vl;
                #pragma unroll
                for (int j = 0; j < 8; ++j) {
                    const unsigned hib = f2bf_bits(ev[j]);
                    const float hif = __builtin_bit_cast(float, hib << 16);
                    const unsigned lob = f2bf_bits(ev[j] - hif);
                    vh[j] = (short)hib;
                    vl[j] = (short)lob;
                }
                wlds[((mt * 2 + 0) * 32 + kt) * 64 + lane] = vh;
                wlds[((mt * 2 + 1) * 32 + kt) * 64 + lane] = vl;
            }
        }
    }
    __syncthreads();

    const float* bi = dir ? bwd_b : fwd_b;
    const float4 bv0 = *(const float4*)(bi + quad * HH + h0);
    const float4 bv1 = *(const float4*)(bi + quad * HH + h0 + 4);
    const float bias0[4] = {bv0.x, bv0.y, bv0.z, bv0.w};
    const float bias1[4] = {bv1.x, bv1.y, bv1.z, bv1.w};

    unsigned* myflg = flg + dir * 64;
    float* exw = ex + wv * 512;

    for (int t = 0; t < SS; ++t) {
        const int s = dir ? (SS - 1 - t) : t;
        const int p = t & 1;

        float4v acc0 = {0.f, 0.f, 0.f, 0.f};
        float4v acc1 = {0.f, 0.f, 0.f, 0.f};

        // ---------- x-part: contiguous fragment loads, reused for both mt ----
        {
            const short8* xh8 = (const short8*)(xef +
                ((size_t)(s * 2 + 0) * BB + b) * 512 + quad * 8);
            const short8* xl8 = (const short8*)(xef +
                ((size_t)(s * 2 + 1) * BB + b) * 512 + quad * 8);
            #pragma unroll
            for (int kt = 0; kt < 16; ++kt) {
                const short8 xh   = xh8[kt * 4];
                const short8 xl   = xl8[kt * 4];
                const short8 whi0 = wlds[((0 * 2 + 0) * 32 + kt) * 64 + lane];
                const short8 wlo0 = wlds[((0 * 2 + 1) * 32 + kt) * 64 + lane];
                const short8 whi1 = wlds[((1 * 2 + 0) * 32 + kt) * 64 + lane];
                const short8 wlo1 = wlds[((1 * 2 + 1) * 32 + kt) * 64 + lane];
                acc0 = __builtin_amdgcn_mfma_f32_16x16x32_bf16(whi0, xh, acc0, 0, 0, 0);
                acc0 = __builtin_amdgcn_mfma_f32_16x16x32_bf16(whi0, xl, acc0, 0, 0, 0);
                acc0 = __builtin_amdgcn_mfma_f32_16x16x32_bf16(wlo0, xh, acc0, 0, 0, 0);
                acc1 = __builtin_amdgcn_mfma_f32_16x16x32_bf16(whi1, xh, acc1, 0, 0, 0);
                acc1 = __builtin_amdgcn_mfma_f32_16x16x32_bf16(whi1, xl, acc1, 0, 0, 0);
                acc1 = __builtin_amdgcn_mfma_f32_16x16x32_bf16(wlo1, xh, acc1, 0, 0, 0);
            }
        }

        // ---------- wait: all 64 WGs of this dir finished step t-1 ----------
        if (t > 0) {
            const unsigned tgt = (unsigned)t;
            unsigned va;
            va = __hip_atomic_load(myflg + lane, __ATOMIC_RELAXED,
                                   __HIP_MEMORY_SCOPE_AGENT);
            while (__any(va < tgt)) {
                __builtin_amdgcn_s_sleep(8);
                va = __hip_atomic_load(myflg + lane, __ATOMIC_RELAXED,
                                       __HIP_MEMORY_SCOPE_AGENT);
            }
            asm volatile("" ::: "memory");
        }

        // ---------- h-part: agent-scope 8B loads, reused for both mt ----------
        {
            const size_t zrow = ((size_t)(p * 2 + dir) * BB + b) * HH + quad * 8;
            const unsigned long long* zhq = (const unsigned long long*)(hspl + zrow);
            const unsigned long long* zlq =
                (const unsigned long long*)(hspl + HSPL_PLANE + zrow);
            #pragma unroll
            for (int kt = 0; kt < 16; ++kt) {
                union { unsigned long long q[2]; short8 v; } uh, ul;
                uh.q[0] = __hip_atomic_load(zhq + kt * 8 + 0, __ATOMIC_RELAXED,
                                            __HIP_MEMORY_SCOPE_AGENT);
                uh.q[1] = __hip_atomic_load(zhq + kt * 8 + 1, __ATOMIC_RELAXED,
                                            __HIP_MEMORY_SCOPE_AGENT);
                ul.q[0] = __hip_atomic_load(zlq + kt * 8 + 0, __ATOMIC_RELAXED,
                                            __HIP_MEMORY_SCOPE_AGENT);
                ul.q[1] = __hip_atomic_load(zlq + kt * 8 + 1, __ATOMIC_RELAXED,
                                            __HIP_MEMORY_SCOPE_AGENT);
                const short8 whi0 = wlds[((0 * 2 + 0) * 32 + 16 + kt) * 64 + lane];
                const short8 wlo0 = wlds[((0 * 2 + 1) * 32 + 16 + kt) * 64 + lane];
                const short8 whi1 = wlds[((1 * 2 + 0) * 32 + 16 + kt) * 64 + lane];
                const short8 wlo1 = wlds[((1 * 2 + 1) * 32 + 16 + kt) * 64 + lane];
                acc0 = __builtin_amdgcn_mfma_f32_16x16x32_bf16(whi0, uh.v, acc0, 0, 0, 0);
                acc0 = __builtin_amdgcn_mfma_f32_16x16x32_bf16(whi0, ul.v, acc0, 0, 0, 0);
                acc0 = __builtin_amdgcn_mfma_f32_16x16x32_bf16(wlo0, uh.v, acc0, 0, 0, 0);
                acc1 = __builtin_amdgcn_mfma_f32_16x16x32_bf16(whi1, uh.v, acc1, 0, 0, 0);
                acc1 = __builtin_amdgcn_mfma_f32_16x16x32_bf16(whi1, ul.v, acc1, 0, 0, 0);
                acc1 = __builtin_amdgcn_mfma_f32_16x16x32_bf16(wlo1, uh.v, acc1, 0, 0, 0);
            }
        }

        // ---------- bias + per-wave exchange (two m-tiles) ----------
        #pragma unroll
        for (int r2 = 0; r2 < 4; ++r2) {
            exw[(quad * 4 + r2) * 16 + nn]       = acc0[r2] + bias0[r2];
            exw[256 + (quad * 4 + r2) * 16 + nn] = acc1[r2] + bias1[r2];
        }
        float pg0[4], pg1[4];
        #pragma unroll
        for (int g_ = 0; g_ < 4; ++g_) {
            pg0[g_] = exw[(g_ * 4 + quad) * 16 + nn];
            pg1[g_] = exw[256 + (g_ * 4 + quad) * 16 + nn];
        }

        const float f0  = sigm_(pg0[0]);
        const float i0  = sigm_(pg0[1]);
        const float ct0 = tanh_(pg0[2]);
        const float o0  = sigm_(pg0[3]);
        const float hn0 = o0 * tanh_((f0 + i0) * ct0);   // faithful: prev cell unused

        const float f1  = sigm_(pg1[0]);
        const float i1  = sigm_(pg1[1]);
        const float ct1 = tanh_(pg1[2]);
        const float o1  = sigm_(pg1[3]);
        const float hn1 = o1 * tanh_((f1 + i1) * ct1);

        const unsigned hib0 = f2bf_bits(hn0);
        const float    hif0 = __builtin_bit_cast(float, hib0 << 16);
        const unsigned lob0 = f2bf_bits(hn0 - hif0);
        const unsigned hib1 = f2bf_bits(hn1);
        const float    hif1 = __builtin_bit_cast(float, hib1 << 16);
        const unsigned lob1 = f2bf_bits(hn1 - hif1);

        // stg layout: [pl(2)][hh8(8)][b(64)]
        stg[(0 * 8 + quad) * 64 + b]     = (unsigned short)hib0;
        stg[(1 * 8 + quad) * 64 + b]     = (unsigned short)lob0;
        stg[(0 * 8 + 4 + quad) * 64 + b] = (unsigned short)hib1;
        stg[(1 * 8 + 4 + quad) * 64 + b] = (unsigned short)lob1;
        hist[(((size_t)dir * SS + s) * HH + h0 + quad) * BB + b]     = hn0;
        hist[(((size_t)dir * SS + s) * HH + h0 + 4 + quad) * BB + b] = hn1;
        __syncthreads();

        // ---------- publish: packed dword write-through stores ----------
        {
            const int plane = tid >> 7;          // 0 hi, 1 lo
            const int d     = tid & 127;
            const int pb    = d & 63;            // b
            const int pr    = d >> 6;            // this thread stores pairs pr, pr+2
            const unsigned v0a = stg[(plane * 8 + pr * 2 + 0) * 64 + pb];
            const unsigned v1a = stg[(plane * 8 + pr * 2 + 1) * 64 + pb];
            const unsigned v0b = stg[(plane * 8 + (pr + 2) * 2 + 0) * 64 + pb];
            const unsigned v1b = stg[(plane * 8 + (pr + 2) * 2 + 1) * 64 + pb];
            const size_t sbase = ((size_t)((p ^ 1) * 2 + dir) * BB + pb) * HH + h0;
            unsigned* dsta = (unsigned*)(hspl + (size_t)plane * HSPL_PLANE
                                         + sbase + pr * 2);
            unsigned* dstb = (unsigned*)(hspl + (size_t)plane * HSPL_PLANE
                                         + sbase + (pr + 2) * 2);
            __hip_atomic_store(dsta, v0a | (v1a << 16), __ATOMIC_RELAXED,
                               __HIP_MEMORY_SCOPE_AGENT);
            __hip_atomic_store(dstb, v0b | (v1b << 16), __ATOMIC_RELAXED,
                               __HIP_MEMORY_SCOPE_AGENT);
        }
        asm volatile("s_waitcnt vmcnt(0)" ::: "memory");
        __syncthreads();
        if (tid == 0)
            __hip_atomic_store(myflg + wlocal, (unsigned)(t + 1),
                               __ATOMIC_RELAXED, __HIP_MEMORY_SCOPE_AGENT);
    }
}

// ---------------------------------------------------------------------------
__global__ __launch_bounds__(256)
void pool_k(const float* __restrict__ hist, float* __restrict__ pooled)
{
    const int i = blockIdx.x * 256 + threadIdx.x;   // i = h*64 + b
    float m = -2.0f;
    for (int s = 0; s < SS; ++s) {
        const float a = hist[(size_t)s * (HH * BB) + i];
        const float c = hist[(size_t)(SS + s) * (HH * BB) + i];
        m = fmaxf(m, tanhf(a * c));
    }
    pooled[i] = m;
}

__global__ __launch_bounds__(256)
void outgemm_k(const float* __restrict__ pooled, const float* __restrict__ Wout,
               const float* __restrict__ bout, float* __restrict__ out)
{
    const int c   = blockIdx.x;
    const int tid = threadIdx.x;
    const int b   = tid & 63;
    const int q   = __builtin_amdgcn_readfirstlane(tid >> 6);
    float p = 0.0f;
    for (int j = 0; j < 128; ++j) {
        const int h = q * 128 + j;
        p = fmaf(pooled[(size_t)h * BB + b], Wout[c * HH + h], p);
    }
    __shared__ float red[4][BB];
    red[q][b] = p;
    __syncthreads();
    if (tid < BB)
        out[tid * CC + c] = red[0][tid] + red[1][tid] + red[2][tid] + red[3][tid] + bout[c];
}

// ---------------------------------------------------------------------------
extern "C" void kernel_launch(void* const* d_in, const int* in_sizes, int n_in,
                              void* d_out, int out_size, void* d_ws, size_t ws_size,
                              hipStream_t stream)
{
    const int*   x     = (const int*)d_in[0];
    const float* embed = (const float*)d_in[1];
    const float* fwd_W = (const float*)d_in[2];
    const float* fwd_b = (const float*)d_in[3];
    const float* bwd_W = (const float*)d_in[4];
    const float* bwd_b = (const float*)d_in[5];
    const float* Wout  = (const float*)d_in[6];
    const float* bout  = (const float*)d_in[7];
    float* out = (float*)d_out;

    char* wsb = (char*)d_ws;
    short*    xef    = (short*)(wsb + OFF_XEF);
    short*    hspl   = (short*)(wsb + OFF_HSPL);
    unsigned* flg    = (unsigned*)(wsb + OFF_FLG);
    float*    hist   = (float*)(wsb + OFF_HIST);
    float*    pooled = (float*)(wsb + OFF_POOLED);   // overlays hspl (dead)

    gather_split_k<<<SS, 256, 0, stream>>>(x, embed, xef);
    zero_k<<<512, 256, 0, stream>>>((unsigned*)(wsb + OFF_HSPL),
                                    (int)((524288 + 1024) / 4));

    hipFuncSetAttribute((const void*)bilstm_recur_k,
                        hipFuncAttributeMaxDynamicSharedMemorySize, 141312);
    void* args[] = {(void*)&xef, (void*)&fwd_W, (void*)&bwd_W,
                    (void*)&fwd_b, (void*)&bwd_b,
                    (void*)&hspl, (void*)&hist, (void*)&flg};
    hipLaunchCooperativeKernel((void*)bilstm_recur_k, dim3(128), dim3(256),
                               args, 141312, stream);

    pool_k<<<128, 256, 0, stream>>>(hist, pooled);
    outgemm_k<<<CC, 256, 0, stream>>>(pooled, Wout, bout, out);
}